// Round 7
// baseline (129.964 us; speedup 1.0000x reference)
//
#include <hip/hip_runtime.h>
#include <hip/hip_bf16.h>

typedef float f32x4 __attribute__((ext_vector_type(4)));
typedef short short8_t __attribute__((ext_vector_type(8)));

// fp32 -> bf16 round-to-nearest-even, two at a time, pure bit ops
__device__ __forceinline__ unsigned int cvt2(float lo, float hi) {
    unsigned int ul = __builtin_bit_cast(unsigned int, lo);
    unsigned int uh = __builtin_bit_cast(unsigned int, hi);
    ul += 0x7FFFu + ((ul >> 16) & 1u);
    uh += 0x7FFFu + ((uh >> 16) & 1u);
    return (ul >> 16) | (uh & 0xFFFF0000u);
}

__device__ __forceinline__ float sq4(f32x4 v, float acc) {
    acc = fmaf(v[0], v[0], acc); acc = fmaf(v[1], v[1], acc);
    acc = fmaf(v[2], v[2], acc); acc = fmaf(v[3], v[3], acc);
    return acc;
}

__device__ __forceinline__ float dot4(f32x4 a, f32x4 b, float acc) {
    acc = fmaf(a[0], b[0], acc); acc = fmaf(a[1], b[1], acc);
    acc = fmaf(a[2], b[2], acc); acc = fmaf(a[3], b[3], acc);
    return acc;
}

__device__ __forceinline__ short8_t pk8(f32x4 a, f32x4 b) {
    union { short8_t s; unsigned int u[4]; } w;
    w.u[0] = cvt2(a[0], a[1]); w.u[1] = cvt2(a[2], a[3]);
    w.u[2] = cvt2(b[0], b[1]); w.u[3] = cvt2(b[2], b[3]);
    return w.s;
}

__device__ __forceinline__ void gload16(const void* g, void* l) {
    __builtin_amdgcn_global_load_lds(
        (const __attribute__((address_space(1))) unsigned int*)g,
        (__attribute__((address_space(3))) unsigned int*)l, 16, 0, 0);
}

// ================= prep: fp32 -> bf16 + row/col stats (one wave per row) ===============
__global__ __launch_bounds__(256)
void prep_kernel(const float* __restrict__ X, const float* __restrict__ P,
                 const float* __restrict__ A, const float* __restrict__ S,
                 short* __restrict__ Xb, short* __restrict__ Pb, short* __restrict__ Ab,
                 float* __restrict__ x2a, float* __restrict__ paa, float* __restrict__ Ba,
                 float* __restrict__ rBana, float* __restrict__ esla, int N, int O)
{
    const int D = 512;
    const int w    = blockIdx.x * 4 + (threadIdx.x >> 6);
    const int lane = threadIdx.x & 63;
    if (w < N) {
        const float* row = X + (size_t)w * D + lane * 8;
        f32x4 u0 = *(const f32x4*)row;
        f32x4 u1 = *(const f32x4*)(row + 4);
        *(short8_t*)(Xb + (size_t)w * D + lane * 8) = pk8(u0, u1);
        float s = sq4(u1, sq4(u0, 0.f));
        #pragma unroll
        for (int m = 1; m < 64; m <<= 1) s += __shfl_xor(s, m, 64);
        if (lane == 0) x2a[w] = s;
    } else if (w < N + O) {
        const int col = w - N;
        const float* prow = P + (size_t)col * D + lane * 8;
        const float* arow = A + (size_t)col * D + lane * 8;
        f32x4 p0 = *(const f32x4*)prow, p1 = *(const f32x4*)(prow + 4);
        f32x4 a0 = *(const f32x4*)arow, a1 = *(const f32x4*)(arow + 4);
        *(short8_t*)(Pb + (size_t)col * D + lane * 8) = pk8(p0, p1);
        *(short8_t*)(Ab + (size_t)col * D + lane * 8) = pk8(a0, a1);
        float sp  = sq4(p1, sq4(p0, 0.f));
        float sa  = sq4(a1, sq4(a0, 0.f));
        float spa = dot4(p1, a1, dot4(p0, a0, 0.f));
        #pragma unroll
        for (int m = 1; m < 64; m <<= 1) {
            sp += __shfl_xor(sp, m, 64);
            sa += __shfl_xor(sa, m, 64);
            spa += __shfl_xor(spa, m, 64);
        }
        if (lane == 0) {
            float B  = 1.f - sp;
            float an = fmaxf(__builtin_amdgcn_sqrtf(sa), 1e-15f);
            paa[col]   = spa;
            Ba[col]    = B;
            rBana[col] = __builtin_amdgcn_rcpf(fmaxf(B * an, 1e-30f));
            esla[col]  = 0.69314718055994531f * expf(S[col]);
        }
    }
}

// ================= main: bf16 dual-GEMM, 2-phase prefetch, BK=32 dbuf ===============
// Tile 64x128, BK=32, LDS double-buffered 2x20KB -> 4 blocks/CU.
// Per buffer: xs [64 rows x 64B] @0, ps [128 x 64B] @4096, as [128 x 64B] @12288.
// Fragment reads at BK=32 are naturally conflict-free (16 rows x 4 chunks cover
// all 32 banks uniformly) -> linear LDS, no swizzle (global_load_lds compatible).
#define BM2 64
#define BN2 128
#define BK2 32
#define BUFB 20480

__device__ __forceinline__ void stage_tiles(const char* Xb, const char* Pb, const char* Ab,
                                            char* buf, int n0, int o0, int ks, int tid,
                                            size_t Db) {
    const size_t kb = (size_t)ks * (BK2 * 2);   // 64 B per K-step
    {
        int row = tid >> 2, ch = tid & 3;       // 64 rows, 4 threads/row
        gload16(Xb + (size_t)(n0 + row) * Db + kb + ch * 16, buf + tid * 16);
    }
    #pragma unroll
    for (int s = 0; s < 2; ++s) {
        int cl = s * 256 + tid;
        int row = cl >> 2, ch = cl & 3;         // 128 rows
        size_t go = (size_t)(o0 + row) * Db + kb + ch * 16;
        gload16(Pb + go, buf + 4096 + cl * 16);
        gload16(Ab + go, buf + 12288 + cl * 16);
    }
}

__global__ __launch_bounds__(256, 4)
void mobius_gemm_kernel(const short* __restrict__ Xb, const short* __restrict__ Pb,
                        const short* __restrict__ Ab,
                        const float* __restrict__ x2a, const float* __restrict__ paa,
                        const float* __restrict__ Ba, const float* __restrict__ rBana,
                        const float* __restrict__ esla,
                        float* __restrict__ out, int N, int O)
{
    const int D = 512;
    __shared__ __align__(16) char smem[2][BUFB];   // 40960 B

    const int nwg = gridDim.x;                     // %8==0 guaranteed by host
    const int q   = nwg >> 3;
    const int swz = (blockIdx.x & 7) * q + (blockIdx.x >> 3);
    const int ncol = O / BN2;                      // col-fastest for L2 x-panel sharing
    const int brow = swz / ncol, bcol = swz % ncol;
    const int n0 = brow * BM2, o0 = bcol * BN2;

    const int tid = threadIdx.x, lane = tid & 63, wid = tid >> 6;
    const int wr = wid >> 1, wc = wid & 1;         // wave tile 32x64

    f32x4 accP[2][4], accA[2][4];
    #pragma unroll
    for (int m = 0; m < 2; m++)
        #pragma unroll
        for (int n = 0; n < 4; n++) { accP[m][n] = (f32x4)0.f; accA[m][n] = (f32x4)0.f; }

    const size_t Db = (size_t)D * 2;               // 1024 B per bf16 row
    const char* Xc = (const char*)Xb;
    const char* Pc = (const char*)Pb;
    const char* Ac = (const char*)Ab;

    const int fr = lane & 15;
    const int fo = (lane >> 4) << 4;               // k-chunk byte offset

    stage_tiles(Xc, Pc, Ac, smem[0], n0, o0, 0, tid, Db);
    __syncthreads();

    int cur = 0;
    const int NK = D / BK2;                        // 16
    for (int ks = 0; ks < NK; ++ks) {
        if (ks + 1 < NK)
            stage_tiles(Xc, Pc, Ac, smem[cur ^ 1], n0, o0, ks + 1, tid, Db);

        const char* xs = smem[cur];
        const char* ps = smem[cur] + 4096;
        const char* as = smem[cur] + 12288;

        short8_t af[2], bp[4], ba[4];
        #pragma unroll
        for (int m = 0; m < 2; m++)
            af[m] = *(const short8_t*)(xs + (wr * 32 + m * 16 + fr) * 64 + fo);
        #pragma unroll
        for (int n = 0; n < 4; n++) {
            bp[n] = *(const short8_t*)(ps + (wc * 64 + n * 16 + fr) * 64 + fo);
            ba[n] = *(const short8_t*)(as + (wc * 64 + n * 16 + fr) * 64 + fo);
        }
        #pragma unroll
        for (int m = 0; m < 2; m++)
            #pragma unroll
            for (int n = 0; n < 4; n++) {
                accP[m][n] = __builtin_amdgcn_mfma_f32_16x16x32_bf16(af[m], bp[n], accP[m][n], 0, 0, 0);
                accA[m][n] = __builtin_amdgcn_mfma_f32_16x16x32_bf16(af[m], ba[n], accA[m][n], 0, 0, 0);
            }

        __syncthreads();   // drains this iter's prefetch (after compute covered it)
        cur ^= 1;
    }

    // ---- epilogue: Mobius dist in regs -> LDS bounce -> coalesced f32x4 stores ----
    const int cl_ = lane & 15, g = lane >> 4;
    float pac[4], Bc[4], rB[4], es[4];
    #pragma unroll
    for (int n = 0; n < 4; n++) {
        int col = o0 + wc * 64 + n * 16 + cl_;
        pac[n] = paa[col]; Bc[n] = Ba[col]; rB[n] = rBana[col]; es[n] = esla[col];
    }
    float* ob = (float*)smem;                      // [64][132] f32 = 33792 B <= 40960
    #pragma unroll
    for (int m = 0; m < 2; m++) {
        #pragma unroll
        for (int r = 0; r < 4; r++) {
            const int row = wr * 32 + m * 16 + g * 4 + r;
            const float x2  = x2a[n0 + row];
            const float ap1 = 1.f + x2;
            const float zs  = 2.f * __builtin_amdgcn_rcpf(fmaxf(1.f - x2, 1e-30f));
            #pragma unroll
            for (int n = 0; n < 4; n++) {
                float xp = accP[m][n][r];
                float xa = accA[m][n][r];
                float Acf = ap1 - (xp + xp);                    // A = 1 - 2xp + x2
                float num = fmaf(Bc[n], xa, -(Acf * pac[n]));   // B*xa - A*pa
                float z   = num * zs * rB[n];
                float az  = fabsf(z);
                float wv  = az + __builtin_amdgcn_sqrtf(fmaf(z, z, 1.f));
                float l   = __builtin_amdgcn_logf(wv);
                ob[row * 132 + wc * 64 + n * 16 + cl_] = copysignf(l, z) * es[n];
            }
        }
    }
    __syncthreads();
    #pragma unroll
    for (int s = 0; s < 8; ++s) {
        int row = s * 8 + (tid >> 5), c = (tid & 31) * 4;
        f32x4 v = *(const f32x4*)(ob + row * 132 + c);
        *(f32x4*)(out + (size_t)(n0 + row) * O + o0 + c) = v;
    }
}

// ================= fallback (known-passing single kernel, R5) ===============
#define BM 128
#define BN 128
#define BK 64
#define PAD 8
#define LDT (BK + PAD)

__global__ __launch_bounds__(256, 2)
void mobius_d2p_kernel(const float* __restrict__ X, const float* __restrict__ P,
                       const float* __restrict__ A, const float* __restrict__ S,
                       float* __restrict__ out, int N, int O, int D)
{
    __shared__ short xs[BM][LDT];
    __shared__ short ps[BM][LDT];
    __shared__ short as_[BM][LDT];
    __shared__ float x2p[BM][2];
    __shared__ float p2p[BM][2];
    __shared__ float pap[BM][2];
    __shared__ float a2p[BM][2];

    const int nwg = gridDim.x;
    int swz = blockIdx.x;
    if ((nwg & 7) == 0) {
        int q = nwg >> 3;
        swz = (blockIdx.x & 7) * q + (blockIdx.x >> 3);
    }
    const int ncol = O / BN;
    const int brow = swz / ncol;
    const int bcol = swz % ncol;
    const int n0 = brow * BM;
    const int o0 = bcol * BN;

    const int tid  = threadIdx.x;
    const int lane = tid & 63;
    const int wid  = tid >> 6;
    const int wr   = wid >> 1;
    const int wc   = wid & 1;

    const int srow = tid >> 1;
    const int sseg = (tid & 1) * 32;

    const float* xg = X + (size_t)(n0 + srow) * D + sseg;
    const float* pg = P + (size_t)(o0 + srow) * D + sseg;
    const float* ag = A + (size_t)(o0 + srow) * D + sseg;

    float accx2 = 0.f, accp2 = 0.f, accpa = 0.f, acca2 = 0.f;

    f32x4 accP[4][4], accA[4][4];
    #pragma unroll
    for (int i = 0; i < 4; i++)
        #pragma unroll
        for (int j = 0; j < 4; j++) { accP[i][j] = (f32x4)0.f; accA[i][j] = (f32x4)0.f; }

    const int frow_a = wr * 64 + (lane & 15);
    const int frow_b = wc * 64 + (lane & 15);
    const int fk     = (lane >> 4) * 8;

    const int nk = D / BK;
    for (int ks = 0; ks < nk; ++ks) {
        const float* xr = xg + ks * BK;
        const float* pr = pg + ks * BK;
        const float* ar = ag + ks * BK;

        #pragma unroll
        for (int j = 0; j < 4; j++) {
            f32x4 u0 = *(const f32x4*)(xr + j * 8);
            f32x4 u1 = *(const f32x4*)(xr + j * 8 + 4);
            accx2 = sq4(u0, accx2); accx2 = sq4(u1, accx2);
            *(short8_t*)&xs[srow][sseg + j * 8] = pk8(u0, u1);
        }
        #pragma unroll
        for (int j = 0; j < 4; j++) {
            f32x4 u0 = *(const f32x4*)(pr + j * 8);
            f32x4 u1 = *(const f32x4*)(pr + j * 8 + 4);
            f32x4 v0 = *(const f32x4*)(ar + j * 8);
            f32x4 v1 = *(const f32x4*)(ar + j * 8 + 4);
            accp2 = sq4(u0, accp2); accp2 = sq4(u1, accp2);
            acca2 = sq4(v0, acca2); acca2 = sq4(v1, acca2);
            accpa = dot4(u0, v0, accpa); accpa = dot4(u1, v1, accpa);
            *(short8_t*)&ps[srow][sseg + j * 8] = pk8(u0, u1);
            *(short8_t*)&as_[srow][sseg + j * 8] = pk8(v0, v1);
        }
        __syncthreads();

        #pragma unroll
        for (int kk = 0; kk < 2; ++kk) {
            const int kof = kk * 32 + fk;
            short8_t af[4], bp[4], ba[4];
            #pragma unroll
            for (int m = 0; m < 4; m++) af[m] = *(const short8_t*)&xs[frow_a + m * 16][kof];
            #pragma unroll
            for (int n = 0; n < 4; n++) {
                bp[n] = *(const short8_t*)&ps[frow_b + n * 16][kof];
                ba[n] = *(const short8_t*)&as_[frow_b + n * 16][kof];
            }
            #pragma unroll
            for (int m = 0; m < 4; m++)
                #pragma unroll
                for (int n = 0; n < 4; n++) {
                    accP[m][n] = __builtin_amdgcn_mfma_f32_16x16x32_bf16(af[m], bp[n], accP[m][n], 0, 0, 0);
                    accA[m][n] = __builtin_amdgcn_mfma_f32_16x16x32_bf16(af[m], ba[n], accA[m][n], 0, 0, 0);
                }
        }
        __syncthreads();
    }

    x2p[srow][tid & 1] = accx2;
    p2p[srow][tid & 1] = accp2;
    pap[srow][tid & 1] = accpa;
    a2p[srow][tid & 1] = acca2;
    __syncthreads();

    const int cl = lane & 15;
    const int g  = lane >> 4;

    float pac[4], Bcv[4], rBan[4], esl[4];
    #pragma unroll
    for (int n = 0; n < 4; n++) {
        int col = wc * 64 + n * 16 + cl;
        float p2 = p2p[col][0] + p2p[col][1];
        float pa = pap[col][0] + pap[col][1];
        float a2 = a2p[col][0] + a2p[col][1];
        float B  = 1.f - p2;
        float an = fmaxf(__builtin_amdgcn_sqrtf(a2), 1e-15f);
        pac[n] = pa; Bcv[n] = B;
        rBan[n] = __builtin_amdgcn_rcpf(fmaxf(B * an, 1e-30f));
        esl[n]  = 0.69314718055994531f * expf(S[o0 + col]);
    }
    float x2r[16];
    #pragma unroll
    for (int m = 0; m < 4; m++)
        #pragma unroll
        for (int r = 0; r < 4; r++) {
            int row = wr * 64 + m * 16 + g * 4 + r;
            x2r[m * 4 + r] = x2p[row][0] + x2p[row][1];
        }

    #pragma unroll
    for (int m = 0; m < 4; m++) {
        #pragma unroll
        for (int r = 0; r < 4; r++) {
            const int row = wr * 64 + m * 16 + g * 4 + r;
            const float x2  = x2r[m * 4 + r];
            const float ap1 = 1.f + x2;
            const float zs  = 2.f * __builtin_amdgcn_rcpf(fmaxf(1.f - x2, 1e-30f));
            float* orow = out + (size_t)(n0 + row) * O + o0 + wc * 64 + cl;
            #pragma unroll
            for (int n = 0; n < 4; n++) {
                float xp = accP[m][n][r];
                float xa = accA[m][n][r];
                float Ac = ap1 - (xp + xp);
                float num = fmaf(Bcv[n], xa, -(Ac * pac[n]));
                float z   = num * zs * rBan[n];
                float az = fabsf(z);
                float w  = az + __builtin_amdgcn_sqrtf(fmaf(z, z, 1.f));
                float l  = __builtin_amdgcn_logf(w);
                orow[n * 16] = copysignf(l, z) * esl[n];
            }
        }
    }
}

extern "C" void kernel_launch(void* const* d_in, const int* in_sizes, int n_in,
                              void* d_out, int out_size, void* d_ws, size_t ws_size,
                              hipStream_t stream) {
    const float* X = (const float*)d_in[0];
    const float* P = (const float*)d_in[1];
    const float* A = (const float*)d_in[2];
    const float* S = (const float*)d_in[3];
    float* out = (float*)d_out;

    const int O = in_sizes[3];
    const int D = in_sizes[1] / O;
    const int N = in_sizes[0] / D;

    // workspace layout
    size_t offP  = (size_t)N * D * 2;
    size_t offA  = offP + (size_t)O * D * 2;
    size_t offx2 = offA + (size_t)O * D * 2;
    size_t offpa = offx2 + (size_t)N * 4;
    size_t offB  = offpa + (size_t)O * 4;
    size_t offrB = offB + (size_t)O * 4;
    size_t offes = offrB + (size_t)O * 4;
    size_t need  = offes + (size_t)O * 4;

    const bool fast = (ws_size >= need) && D == 512 &&
                      (N % BM2 == 0) && (O % BN2 == 0) &&
                      (((N / BM2) * (O / BN2)) % 8 == 0) && ((N + O) % 4 == 0);

    if (fast) {
        char* ws = (char*)d_ws;
        short* Xb = (short*)ws;
        short* Pb = (short*)(ws + offP);
        short* Ab = (short*)(ws + offA);
        float* x2a = (float*)(ws + offx2);
        float* paa = (float*)(ws + offpa);
        float* Ba  = (float*)(ws + offB);
        float* rBa = (float*)(ws + offrB);
        float* esl = (float*)(ws + offes);

        prep_kernel<<<dim3((N + O) / 4), dim3(256), 0, stream>>>(
            X, P, A, S, Xb, Pb, Ab, x2a, paa, Ba, rBa, esl, N, O);
        mobius_gemm_kernel<<<dim3((N / BM2) * (O / BN2)), dim3(256), 0, stream>>>(
            Xb, Pb, Ab, x2a, paa, Ba, rBa, esl, out, N, O);
    } else {
        const int nwg = (N / BM) * (O / BN);
        mobius_d2p_kernel<<<dim3(nwg), dim3(256), 0, stream>>>(X, P, A, S, out, N, O, D);
    }
}

// Round 8
// 110.989 us; speedup vs baseline: 1.1710x; 1.1710x over previous
//
#include <hip/hip_runtime.h>
#include <hip/hip_bf16.h>

typedef float f32x4 __attribute__((ext_vector_type(4)));
typedef short short8_t __attribute__((ext_vector_type(8)));

// fp32 -> bf16 round-to-nearest-even, two at a time, pure bit ops
__device__ __forceinline__ unsigned int cvt2(float lo, float hi) {
    unsigned int ul = __builtin_bit_cast(unsigned int, lo);
    unsigned int uh = __builtin_bit_cast(unsigned int, hi);
    ul += 0x7FFFu + ((ul >> 16) & 1u);
    uh += 0x7FFFu + ((uh >> 16) & 1u);
    return (ul >> 16) | (uh & 0xFFFF0000u);
}

__device__ __forceinline__ float sq4(f32x4 v, float acc) {
    acc = fmaf(v[0], v[0], acc); acc = fmaf(v[1], v[1], acc);
    acc = fmaf(v[2], v[2], acc); acc = fmaf(v[3], v[3], acc);
    return acc;
}

__device__ __forceinline__ float dot4(f32x4 a, f32x4 b, float acc) {
    acc = fmaf(a[0], b[0], acc); acc = fmaf(a[1], b[1], acc);
    acc = fmaf(a[2], b[2], acc); acc = fmaf(a[3], b[3], acc);
    return acc;
}

__device__ __forceinline__ short8_t pk8(f32x4 a, f32x4 b) {
    union { short8_t s; unsigned int u[4]; } w;
    w.u[0] = cvt2(a[0], a[1]); w.u[1] = cvt2(a[2], a[3]);
    w.u[2] = cvt2(b[0], b[1]); w.u[3] = cvt2(b[2], b[3]);
    return w.s;
}

__device__ __forceinline__ void gload16(const void* g, void* l) {
    __builtin_amdgcn_global_load_lds(
        (const __attribute__((address_space(1))) unsigned int*)g,
        (__attribute__((address_space(3))) unsigned int*)l, 16, 0, 0);
}

// ================= prep: fp32 -> bf16 + row/col stats (one wave per row) ===============
__global__ __launch_bounds__(256)
void prep_kernel(const float* __restrict__ X, const float* __restrict__ P,
                 const float* __restrict__ A, const float* __restrict__ S,
                 short* __restrict__ Xb, short* __restrict__ Pb, short* __restrict__ Ab,
                 float* __restrict__ x2a, float* __restrict__ paa, float* __restrict__ Ba,
                 float* __restrict__ rBana, float* __restrict__ esla, int N, int O)
{
    const int D = 512;
    const int w    = blockIdx.x * 4 + (threadIdx.x >> 6);
    const int lane = threadIdx.x & 63;
    if (w < N) {
        const float* row = X + (size_t)w * D + lane * 8;
        f32x4 u0 = *(const f32x4*)row;
        f32x4 u1 = *(const f32x4*)(row + 4);
        *(short8_t*)(Xb + (size_t)w * D + lane * 8) = pk8(u0, u1);
        float s = sq4(u1, sq4(u0, 0.f));
        #pragma unroll
        for (int m = 1; m < 64; m <<= 1) s += __shfl_xor(s, m, 64);
        if (lane == 0) x2a[w] = s;
    } else if (w < N + O) {
        const int col = w - N;
        const float* prow = P + (size_t)col * D + lane * 8;
        const float* arow = A + (size_t)col * D + lane * 8;
        f32x4 p0 = *(const f32x4*)prow, p1 = *(const f32x4*)(prow + 4);
        f32x4 a0 = *(const f32x4*)arow, a1 = *(const f32x4*)(arow + 4);
        *(short8_t*)(Pb + (size_t)col * D + lane * 8) = pk8(p0, p1);
        *(short8_t*)(Ab + (size_t)col * D + lane * 8) = pk8(a0, a1);
        float sp  = sq4(p1, sq4(p0, 0.f));
        float sa  = sq4(a1, sq4(a0, 0.f));
        float spa = dot4(p1, a1, dot4(p0, a0, 0.f));
        #pragma unroll
        for (int m = 1; m < 64; m <<= 1) {
            sp += __shfl_xor(sp, m, 64);
            sa += __shfl_xor(sa, m, 64);
            spa += __shfl_xor(spa, m, 64);
        }
        if (lane == 0) {
            float B  = 1.f - sp;
            float an = fmaxf(__builtin_amdgcn_sqrtf(sa), 1e-15f);
            paa[col]   = spa;
            Ba[col]    = B;
            rBana[col] = __builtin_amdgcn_rcpf(fmaxf(B * an, 1e-30f));
            esla[col]  = 0.69314718055994531f * expf(S[col]);
        }
    }
}

// ================= main: bf16 dual-GEMM, 128x128 tile, BK=64, 1-phase ===============
// LDS: X[128]x128B @0, P[128]x128B @16384, A[128]x128B @32768 = 49152 B.
// XOR chunk swizzle (ch ^ (row&7)) both sides (pre-swizzled global src for
// global_load_lds linear dst + swizzled ds_read addr) -> conflict-free b128 reads.
#define BM2 128
#define BN2 128
#define BK2 64

__global__ __launch_bounds__(256, 2)
void mobius_gemm_kernel(const short* __restrict__ Xb, const short* __restrict__ Pb,
                        const short* __restrict__ Ab,
                        const float* __restrict__ x2a, const float* __restrict__ paa,
                        const float* __restrict__ Ba, const float* __restrict__ rBana,
                        const float* __restrict__ esla,
                        float* __restrict__ out, int N, int O)
{
    const int D = 512;
    __shared__ __align__(16) char smem[3 * BM2 * BK2 * 2];   // 49152 B
    char* xs = smem;
    char* ps = smem + 16384;
    char* as = smem + 32768;

    const int nwg = gridDim.x;                     // %8==0 guaranteed by host
    const int q   = nwg >> 3;
    const int swz = (blockIdx.x & 7) * q + (blockIdx.x >> 3);
    const int ncol = O / BN2;                      // col-fastest for L2 x-panel sharing
    const int brow = swz / ncol, bcol = swz % ncol;
    const int n0 = brow * BM2, o0 = bcol * BN2;

    const int tid = threadIdx.x, lane = tid & 63, wid = tid >> 6;
    const int wr = wid >> 1, wc = wid & 1;         // wave tile 64x64

    f32x4 accP[4][4], accA[4][4];
    #pragma unroll
    for (int m = 0; m < 4; m++)
        #pragma unroll
        for (int n = 0; n < 4; n++) { accP[m][n] = (f32x4)0.f; accA[m][n] = (f32x4)0.f; }

    const size_t Db = (size_t)D * 2;               // 1024 B per bf16 row
    const char* Xc = (const char*)Xb;
    const char* Pc = (const char*)Pb;
    const char* Ac = (const char*)Ab;

    const int fr = lane & 15;
    const int fo = (lane >> 4) << 4;               // k-chunk byte offset within 64B half

    for (int ks = 0; ks < D / BK2; ++ks) {
        const size_t kb = (size_t)ks * (BK2 * 2);  // 128 B per K-step
        #pragma unroll
        for (int s = 0; s < 4; ++s) {              // 128 rows x 8 chunks per matrix
            int cl = s * 256 + tid, row = cl >> 3, ch = cl & 7;
            size_t rowoff = (size_t)row * Db + kb + (size_t)((ch ^ (row & 7)) << 4);
            gload16(Xc + (size_t)n0 * Db + rowoff, xs + cl * 16);
            gload16(Pc + (size_t)o0 * Db + rowoff, ps + cl * 16);
            gload16(Ac + (size_t)o0 * Db + rowoff, as + cl * 16);
        }
        __syncthreads();                           // drains vmcnt before barrier

        #pragma unroll
        for (int kk = 0; kk < 2; ++kk) {
            const int kx = (kk * 64 + fo) ^ ((lane & 7) << 4);
            short8_t af[4], bp[4], ba[4];
            #pragma unroll
            for (int m = 0; m < 4; m++)
                af[m] = *(const short8_t*)(xs + ((wr * 64 + m * 16 + fr) << 7) + kx);
            #pragma unroll
            for (int n = 0; n < 4; n++) {
                bp[n] = *(const short8_t*)(ps + ((wc * 64 + n * 16 + fr) << 7) + kx);
                ba[n] = *(const short8_t*)(as + ((wc * 64 + n * 16 + fr) << 7) + kx);
            }
            #pragma unroll
            for (int m = 0; m < 4; m++)
                #pragma unroll
                for (int n = 0; n < 4; n++) {
                    accP[m][n] = __builtin_amdgcn_mfma_f32_16x16x32_bf16(af[m], bp[n], accP[m][n], 0, 0, 0);
                    accA[m][n] = __builtin_amdgcn_mfma_f32_16x16x32_bf16(af[m], ba[n], accA[m][n], 0, 0, 0);
                }
        }
        __syncthreads();
    }

    // ---- epilogue: two-pass LDS bounce (64 rows each) -> coalesced f32x4 stores ----
    const int cl_ = lane & 15, g = lane >> 4;
    float pac[4], Bc[4], rB[4], es[4];
    #pragma unroll
    for (int n = 0; n < 4; n++) {
        int col = o0 + wc * 64 + n * 16 + cl_;
        pac[n] = paa[col]; Bc[n] = Ba[col]; rB[n] = rBana[col]; es[n] = esla[col];
    }
    float* ob = (float*)smem;                      // [64][132] f32 = 33792 B <= 49152
    #pragma unroll
    for (int p = 0; p < 2; ++p) {
        if (wr == p) {
            #pragma unroll
            for (int m = 0; m < 4; m++) {
                #pragma unroll
                for (int r = 0; r < 4; r++) {
                    const int lrow = m * 16 + g * 4 + r;
                    const float x2  = x2a[n0 + p * 64 + lrow];
                    const float ap1 = 1.f + x2;
                    const float zs  = 2.f * __builtin_amdgcn_rcpf(fmaxf(1.f - x2, 1e-30f));
                    #pragma unroll
                    for (int n = 0; n < 4; n++) {
                        float xp = accP[m][n][r];
                        float xa = accA[m][n][r];
                        float Acf = ap1 - (xp + xp);                    // A = 1 - 2xp + x2
                        float num = fmaf(Bc[n], xa, -(Acf * pac[n]));   // B*xa - A*pa
                        float z   = num * zs * rB[n];
                        float az  = fabsf(z);
                        float wv  = az + __builtin_amdgcn_sqrtf(fmaf(z, z, 1.f));
                        float l   = __builtin_amdgcn_logf(wv);
                        ob[lrow * 132 + wc * 64 + n * 16 + cl_] = copysignf(l, z) * es[n];
                    }
                }
            }
        }
        __syncthreads();
        #pragma unroll
        for (int s = 0; s < 8; ++s) {
            int row = s * 8 + (tid >> 5), c = (tid & 31) * 4;
            f32x4 v = *(const f32x4*)(ob + row * 132 + c);
            *(f32x4*)(out + (size_t)(n0 + p * 64 + row) * O + o0 + c) = v;
        }
        if (p == 0) __syncthreads();
    }
}

// ================= fallback (known-passing single kernel, R5) ===============
#define BM 128
#define BN 128
#define BK 64
#define PAD 8
#define LDT (BK + PAD)

__global__ __launch_bounds__(256, 2)
void mobius_d2p_kernel(const float* __restrict__ X, const float* __restrict__ P,
                       const float* __restrict__ A, const float* __restrict__ S,
                       float* __restrict__ out, int N, int O, int D)
{
    __shared__ short xs[BM][LDT];
    __shared__ short ps[BM][LDT];
    __shared__ short as_[BM][LDT];
    __shared__ float x2p[BM][2];
    __shared__ float p2p[BM][2];
    __shared__ float pap[BM][2];
    __shared__ float a2p[BM][2];

    const int nwg = gridDim.x;
    int swz = blockIdx.x;
    if ((nwg & 7) == 0) {
        int q = nwg >> 3;
        swz = (blockIdx.x & 7) * q + (blockIdx.x >> 3);
    }
    const int ncol = O / BN;
    const int brow = swz / ncol;
    const int bcol = swz % ncol;
    const int n0 = brow * BM;
    const int o0 = bcol * BN;

    const int tid  = threadIdx.x;
    const int lane = tid & 63;
    const int wid  = tid >> 6;
    const int wr   = wid >> 1;
    const int wc   = wid & 1;

    const int srow = tid >> 1;
    const int sseg = (tid & 1) * 32;

    const float* xg = X + (size_t)(n0 + srow) * D + sseg;
    const float* pg = P + (size_t)(o0 + srow) * D + sseg;
    const float* ag = A + (size_t)(o0 + srow) * D + sseg;

    float accx2 = 0.f, accp2 = 0.f, accpa = 0.f, acca2 = 0.f;

    f32x4 accP[4][4], accA[4][4];
    #pragma unroll
    for (int i = 0; i < 4; i++)
        #pragma unroll
        for (int j = 0; j < 4; j++) { accP[i][j] = (f32x4)0.f; accA[i][j] = (f32x4)0.f; }

    const int frow_a = wr * 64 + (lane & 15);
    const int frow_b = wc * 64 + (lane & 15);
    const int fk     = (lane >> 4) * 8;

    const int nk = D / BK;
    for (int ks = 0; ks < nk; ++ks) {
        const float* xr = xg + ks * BK;
        const float* pr = pg + ks * BK;
        const float* ar = ag + ks * BK;

        #pragma unroll
        for (int j = 0; j < 4; j++) {
            f32x4 u0 = *(const f32x4*)(xr + j * 8);
            f32x4 u1 = *(const f32x4*)(xr + j * 8 + 4);
            accx2 = sq4(u0, accx2); accx2 = sq4(u1, accx2);
            *(short8_t*)&xs[srow][sseg + j * 8] = pk8(u0, u1);
        }
        #pragma unroll
        for (int j = 0; j < 4; j++) {
            f32x4 u0 = *(const f32x4*)(pr + j * 8);
            f32x4 u1 = *(const f32x4*)(pr + j * 8 + 4);
            f32x4 v0 = *(const f32x4*)(ar + j * 8);
            f32x4 v1 = *(const f32x4*)(ar + j * 8 + 4);
            accp2 = sq4(u0, accp2); accp2 = sq4(u1, accp2);
            acca2 = sq4(v0, acca2); acca2 = sq4(v1, acca2);
            accpa = dot4(u0, v0, accpa); accpa = dot4(u1, v1, accpa);
            *(short8_t*)&ps[srow][sseg + j * 8] = pk8(u0, u1);
            *(short8_t*)&as_[srow][sseg + j * 8] = pk8(v0, v1);
        }
        __syncthreads();

        #pragma unroll
        for (int kk = 0; kk < 2; ++kk) {
            const int kof = kk * 32 + fk;
            short8_t af[4], bp[4], ba[4];
            #pragma unroll
            for (int m = 0; m < 4; m++) af[m] = *(const short8_t*)&xs[frow_a + m * 16][kof];
            #pragma unroll
            for (int n = 0; n < 4; n++) {
                bp[n] = *(const short8_t*)&ps[frow_b + n * 16][kof];
                ba[n] = *(const short8_t*)&as_[frow_b + n * 16][kof];
            }
            #pragma unroll
            for (int m = 0; m < 4; m++)
                #pragma unroll
                for (int n = 0; n < 4; n++) {
                    accP[m][n] = __builtin_amdgcn_mfma_f32_16x16x32_bf16(af[m], bp[n], accP[m][n], 0, 0, 0);
                    accA[m][n] = __builtin_amdgcn_mfma_f32_16x16x32_bf16(af[m], ba[n], accA[m][n], 0, 0, 0);
                }
        }
        __syncthreads();
    }

    x2p[srow][tid & 1] = accx2;
    p2p[srow][tid & 1] = accp2;
    pap[srow][tid & 1] = accpa;
    a2p[srow][tid & 1] = acca2;
    __syncthreads();

    const int cl = lane & 15;
    const int g  = lane >> 4;

    float pac[4], Bcv[4], rBan[4], esl[4];
    #pragma unroll
    for (int n = 0; n < 4; n++) {
        int col = wc * 64 + n * 16 + cl;
        float p2 = p2p[col][0] + p2p[col][1];
        float pa = pap[col][0] + pap[col][1];
        float a2 = a2p[col][0] + a2p[col][1];
        float B  = 1.f - p2;
        float an = fmaxf(__builtin_amdgcn_sqrtf(a2), 1e-15f);
        pac[n] = pa; Bcv[n] = B;
        rBan[n] = __builtin_amdgcn_rcpf(fmaxf(B * an, 1e-30f));
        esl[n]  = 0.69314718055994531f * expf(S[o0 + col]);
    }
    float x2r[16];
    #pragma unroll
    for (int m = 0; m < 4; m++)
        #pragma unroll
        for (int r = 0; r < 4; r++) {
            int row = wr * 64 + m * 16 + g * 4 + r;
            x2r[m * 4 + r] = x2p[row][0] + x2p[row][1];
        }

    #pragma unroll
    for (int m = 0; m < 4; m++) {
        #pragma unroll
        for (int r = 0; r < 4; r++) {
            const int row = wr * 64 + m * 16 + g * 4 + r;
            const float x2  = x2r[m * 4 + r];
            const float ap1 = 1.f + x2;
            const float zs  = 2.f * __builtin_amdgcn_rcpf(fmaxf(1.f - x2, 1e-30f));
            float* orow = out + (size_t)(n0 + row) * O + o0 + wc * 64 + cl;
            #pragma unroll
            for (int n = 0; n < 4; n++) {
                float xp = accP[m][n][r];
                float xa = accA[m][n][r];
                float Ac = ap1 - (xp + xp);
                float num = fmaf(Bcv[n], xa, -(Ac * pac[n]));
                float z   = num * zs * rBan[n];
                float az = fabsf(z);
                float w  = az + __builtin_amdgcn_sqrtf(fmaf(z, z, 1.f));
                float l  = __builtin_amdgcn_logf(w);
                orow[n * 16] = copysignf(l, z) * esl[n];
            }
        }
    }
}

extern "C" void kernel_launch(void* const* d_in, const int* in_sizes, int n_in,
                              void* d_out, int out_size, void* d_ws, size_t ws_size,
                              hipStream_t stream) {
    const float* X = (const float*)d_in[0];
    const float* P = (const float*)d_in[1];
    const float* A = (const float*)d_in[2];
    const float* S = (const float*)d_in[3];
    float* out = (float*)d_out;

    const int O = in_sizes[3];
    const int D = in_sizes[1] / O;
    const int N = in_sizes[0] / D;

    // workspace layout
    size_t offP  = (size_t)N * D * 2;
    size_t offA  = offP + (size_t)O * D * 2;
    size_t offx2 = offA + (size_t)O * D * 2;
    size_t offpa = offx2 + (size_t)N * 4;
    size_t offB  = offpa + (size_t)O * 4;
    size_t offrB = offB + (size_t)O * 4;
    size_t offes = offrB + (size_t)O * 4;
    size_t need  = offes + (size_t)O * 4;

    const bool fast = (ws_size >= need) && D == 512 &&
                      (N % BM2 == 0) && (O % BN2 == 0) &&
                      (((N / BM2) * (O / BN2)) % 8 == 0) && ((N + O) % 4 == 0);

    if (fast) {
        char* ws = (char*)d_ws;
        short* Xb = (short*)ws;
        short* Pb = (short*)(ws + offP);
        short* Ab = (short*)(ws + offA);
        float* x2a = (float*)(ws + offx2);
        float* paa = (float*)(ws + offpa);
        float* Ba  = (float*)(ws + offB);
        float* rBa = (float*)(ws + offrB);
        float* esl = (float*)(ws + offes);

        prep_kernel<<<dim3((N + O) / 4), dim3(256), 0, stream>>>(
            X, P, A, S, Xb, Pb, Ab, x2a, paa, Ba, rBa, esl, N, O);
        mobius_gemm_kernel<<<dim3((N / BM2) * (O / BN2)), dim3(256), 0, stream>>>(
            Xb, Pb, Ab, x2a, paa, Ba, rBa, esl, out, N, O);
    } else {
        const int nwg = (N / BM) * (O / BN);
        mobius_d2p_kernel<<<dim3(nwg), dim3(256), 0, stream>>>(X, P, A, S, out, N, O, D);
    }
}